// Round 1
// baseline (148.142 us; speedup 1.0000x reference)
//
#include <hip/hip_runtime.h>
#include <hip/hip_bf16.h>

// out[b,c,h,w] = (1/64) * sum_n sum_p Fy[b,n,h,p] * sum_q Fx[b,n,w,q] * patches[b,n,c,p,q]
// Fx[w,q] = exp(-12.5*(w - gx - (q-7.5))^2) / (Zx[q] + 1e-7)
// Zx[q]   = sum over integer coords c in [-8,263] of exp(-12.5*(c - mu)^2), mu = gx + q - 7.5
// sigma=0.2 => support radius 2 px captures everything to <1e-20 relative.

#define IMG 256
#define NB 64

__global__ __launch_bounds__(256) void brush_splat(
        const float* __restrict__ brushes,   // [32,64,2]
        const float* __restrict__ patches,   // [32,64,3,16,16]
        float* __restrict__ out)             // [32,3,256,256]
{
    const int b = blockIdx.y;
    const int h = blockIdx.x;
    const int w = threadIdx.x;

    __shared__ float gxs[NB], gys[NB];
    __shared__ float invZx[NB][16], invZy[NB][16];

    // Setup: 64 brushes * 2 axes * 16 taps = 2048 normalizers; 8 per thread.
    for (int i = threadIdx.x; i < NB * 32; i += 256) {
        const int n = i >> 5;
        const int k = i & 31;
        const int axis = k >> 4;
        const int q = k & 15;
        const float g = brushes[((b << 6) + n) * 2 + axis] * 256.0f;
        const float mu = g + (float)q - 7.5f;
        const float fl = floorf(mu);
        float Z = 0.0f;
#pragma unroll
        for (int d = -1; d <= 2; ++d) {
            const float c = fl + (float)d;
            if (c >= -8.0f && c <= 263.0f) {
                const float t = c - mu;
                Z += __expf(-12.5f * t * t);
            }
        }
        const float inv = 1.0f / (Z + 1e-7f);
        if (axis == 0) invZx[n][q] = inv; else invZy[n][q] = inv;
    }
    if (threadIdx.x < NB) {
        const int n = threadIdx.x;
        gxs[n] = brushes[((b << 6) + n) * 2 + 0] * 256.0f;
        gys[n] = brushes[((b << 6) + n) * 2 + 1] * 256.0f;
    }
    __syncthreads();

    float acc0 = 0.0f, acc1 = 0.0f, acc2 = 0.0f;
    const float fh = (float)h, fw = (float)w;

    for (int n = 0; n < NB; ++n) {
        // p-taps exist iff exists p in [0,15] with |ay - p| <= 2  ->  ay in [-2,17].
        const float ay = fh - gys[n] + 7.5f;   // block-uniform test: cheap skip
        if (ay < -2.0f || ay > 17.0f) continue;
        const float ax = fw - gxs[n] + 7.5f;   // per-lane test
        if (ax < -2.0f || ax > 17.0f) continue;

        int qlo = (int)ceilf(ax - 2.0f); if (qlo < 0) qlo = 0;
        int qhi = (int)floorf(ax + 2.0f); if (qhi > 15) qhi = 15;
        int plo = (int)ceilf(ay - 2.0f); if (plo < 0) plo = 0;
        int phi = (int)floorf(ay + 2.0f); if (phi > 15) phi = 15;
        const int nq = qhi - qlo + 1;          // <= 5

        float wx[5];
        for (int j = 0; j < nq; ++j) {
            const float d = ax - (float)(qlo + j);
            wx[j] = __expf(-12.5f * d * d) * invZx[n][qlo + j];
        }

        const float* pb = patches + ((((b << 6) + n) * 3) << 8);  // + c*256 + p*16 + q
        for (int p = plo; p <= phi; ++p) {
            const float d = ay - (float)p;
            const float wy = __expf(-12.5f * d * d) * invZy[n][p];
            const float* row = pb + (p << 4) + qlo;
            float s0 = 0.0f, s1 = 0.0f, s2 = 0.0f;
            for (int j = 0; j < nq; ++j) {
                const float wxj = wx[j];
                s0 += wxj * row[j];
                s1 += wxj * row[256 + j];
                s2 += wxj * row[512 + j];
            }
            acc0 += wy * s0;
            acc1 += wy * s1;
            acc2 += wy * s2;
        }
    }

    const float scale = 1.0f / 64.0f;
    float* ob = out + ((size_t)(b * 3) << 16) + (h << 8) + w;
    ob[0]           = acc0 * scale;
    ob[1 << 16]     = acc1 * scale;
    ob[2 << 16]     = acc2 * scale;
}

extern "C" void kernel_launch(void* const* d_in, const int* in_sizes, int n_in,
                              void* d_out, int out_size, void* d_ws, size_t ws_size,
                              hipStream_t stream) {
    const float* brushes = (const float*)d_in[0];
    const float* patches = (const float*)d_in[1];
    float* out = (float*)d_out;
    dim3 grid(IMG, 32);   // (h, b)
    dim3 block(IMG);      // w
    brush_splat<<<grid, block, 0, stream>>>(brushes, patches, out);
}

// Round 2
// 84.208 us; speedup vs baseline: 1.7592x; 1.7592x over previous
//
#include <hip/hip_runtime.h>
#include <hip/hip_bf16.h>

// Scatter formulation: out[b,c,h,w] = (1/64) Σ_n Σ_p wy[h,p] Σ_q wx[w,q] patch[b,n,c,p,q]
// sigma=0.2 => exp(-12.5 d^2): support radius 2 px => each brush touches a
// <=20x20 pixel window. One block per (b,n) brush; separable contraction in
// LDS; atomicAdd into zero-initialized output.

#define NW 20   // max window extent per axis

__global__ __launch_bounds__(256) void brush_scatter(
        const float* __restrict__ brushes,   // [32,64,2]
        const float* __restrict__ patches,   // [32,64,3,16,16]
        float* __restrict__ out)             // [32,3,256,256], pre-zeroed
{
    const int bn = blockIdx.x;       // b*64 + n
    const int b  = bn >> 6;
    const int tid = threadIdx.x;

    // stride-20 floats (80B) keeps float4 alignment and spreads LDS banks
    __shared__ float sp [3 * 16 * 20];   // patch [c][p][q(16, pad 20)]
    __shared__ float wxs[NW * 20];       // [wi][q]
    __shared__ float wys[NW * 20];       // [hi][p]
    __shared__ float T  [3 * NW * 20];   // [c][wi][p]
    __shared__ float invZx[16], invZy[16];

    const float gx = brushes[bn * 2 + 0] * 256.0f;
    const float gy = brushes[bn * 2 + 1] * 256.0f;
    const int x0   = max(0, (int)ceilf(gx - 9.5f));
    const int y0   = max(0, (int)ceilf(gy - 9.5f));
    const int xmax = min(255, (int)floorf(gx + 9.5f));
    const int ymax = min(255, (int)floorf(gy + 9.5f));

    // ---- stage 0: stage patch into LDS; compute normalizers -------------
    const float* pb = patches + (size_t)bn * 768;
    for (int t = tid; t < 768; t += 256) {
        const int q = t & 15, cp = t >> 4;
        sp[cp * 20 + q] = pb[t];
    }
    if (tid < 32) {
        const int axis = tid >> 4, q = tid & 15;
        const float g  = axis ? gy : gx;
        const float mu = g + (float)q - 7.5f;
        const float fl = floorf(mu);
        float Z = 0.0f;
#pragma unroll
        for (int d = -1; d <= 2; ++d) {
            const float c = fl + (float)d;
            if (c >= -8.0f && c <= 263.0f) {   // padded coord range
                const float u = c - mu;
                Z += __expf(-12.5f * u * u);
            }
        }
        const float inv = 1.0f / (Z + 1e-7f);
        if (axis) invZy[q] = inv; else invZx[q] = inv;
    }
    __syncthreads();

    // ---- stage 1: weights wx[wi][q], wy[hi][p] (2*320 entries) ----------
    for (int t = tid; t < 2 * NW * 16; t += 256) {
        if (t < NW * 16) {
            const int wi = t >> 4, q = t & 15;
            const float d = (float)(x0 + wi) - gx - ((float)q - 7.5f);
            wxs[wi * 20 + q] = __expf(-12.5f * d * d) * invZx[q];
        } else {
            const int r = t - NW * 16;
            const int hi = r >> 4, p = r & 15;
            const float d = (float)(y0 + hi) - gy - ((float)p - 7.5f);
            wys[hi * 20 + p] = __expf(-12.5f * d * d) * invZy[p];
        }
    }
    __syncthreads();

    // ---- stage 2: T[c][wi][p] = Σ_q wxs[wi][q] * sp[c][p][q] ------------
    for (int t = tid; t < 3 * NW * 16; t += 256) {      // 960 elems
        const int p  = t & 15;
        const int cw = t >> 4;          // 0..59
        const int wi = cw % NW;
        const int c  = cw / NW;
        const float4* a = (const float4*)&sp [(c * 16 + p) * 20];
        const float4* x = (const float4*)&wxs[wi * 20];
        float s = 0.0f;
#pragma unroll
        for (int k = 0; k < 4; ++k) {
            const float4 av = a[k], xv = x[k];
            s += av.x * xv.x + av.y * xv.y + av.z * xv.z + av.w * xv.w;
        }
        T[(c * NW + wi) * 20 + p] = s;
    }
    __syncthreads();

    // ---- stage 3: out[b,c,y0+hi,x0+wi] += (1/64) Σ_p wys[hi][p]*T[c][wi][p]
    for (int t = tid; t < 3 * NW * NW; t += 256) {      // 1200 elems
        const int wi  = t % NW;
        const int chi = t / NW;
        const int hi  = chi % NW;
        const int c   = chi / NW;
        const int w = x0 + wi, h = y0 + hi;
        if (w > xmax || h > ymax) continue;
        const float4* tv = (const float4*)&T  [(c * NW + wi) * 20];
        const float4* yv = (const float4*)&wys[hi * 20];
        float s = 0.0f;
#pragma unroll
        for (int k = 0; k < 4; ++k) {
            const float4 a = tv[k], x = yv[k];
            s += a.x * x.x + a.y * x.y + a.z * x.z + a.w * x.w;
        }
        atomicAdd(&out[(((size_t)(b * 3 + c)) << 16) + (h << 8) + w],
                  s * (1.0f / 64.0f));
    }
}

extern "C" void kernel_launch(void* const* d_in, const int* in_sizes, int n_in,
                              void* d_out, int out_size, void* d_ws, size_t ws_size,
                              hipStream_t stream) {
    const float* brushes = (const float*)d_in[0];
    const float* patches = (const float*)d_in[1];
    float* out = (float*)d_out;
    hipMemsetAsync(out, 0, (size_t)out_size * sizeof(float), stream);
    brush_scatter<<<dim3(32 * 64), dim3(256), 0, stream>>>(brushes, patches, out);
}